// Round 6
// baseline (313.823 us; speedup 1.0000x reference)
//
#include <hip/hip_runtime.h>

constexpr int FIN = 512;
constexpr int HID = 16;
constexpr int NC  = 7;

// ---------------- CSR build ----------------

__global__ void k_hist(const int* __restrict__ dst, int* __restrict__ cnt, int E) {
    int e = blockIdx.x * 256 + threadIdx.x;
    if (e < E) atomicAdd(&cnt[dst[e]], 1);
}

__global__ void k_bsum(const int* __restrict__ cnt, int* __restrict__ bsum, int N) {
    int i = blockIdx.x * 256 + threadIdx.x;
    int v = (i < N) ? cnt[i] : 0;
#pragma unroll
    for (int o = 1; o < 64; o <<= 1) v += __shfl_xor(v, o);
    __shared__ int ws_[4];
    if ((threadIdx.x & 63) == 0) ws_[threadIdx.x >> 6] = v;
    __syncthreads();
    if (threadIdx.x == 0) bsum[blockIdx.x] = ws_[0] + ws_[1] + ws_[2] + ws_[3];
}

__global__ void k_scanb(const int* __restrict__ bsum, int* __restrict__ boff, int nb) {
    __shared__ int s[1024];
    int t = threadIdx.x;
    int mine = (t < nb) ? bsum[t] : 0;
    s[t] = mine;
    __syncthreads();
    for (int o = 1; o < 1024; o <<= 1) {
        int v = (t >= o) ? s[t - o] : 0;
        __syncthreads();
        s[t] += v;
        __syncthreads();
    }
    if (t < nb) boff[t] = s[t] - mine;  // exclusive
}

__global__ void k_rowptr(const int* __restrict__ cnt, const int* __restrict__ boff,
                         int* __restrict__ rowptr, int* __restrict__ cursor,
                         float* __restrict__ dinv, int N, int E) {
    int i = blockIdx.x * 256 + threadIdx.x;
    int v = (i < N) ? cnt[i] : 0;
    int lane = threadIdx.x & 63, w = threadIdx.x >> 6;
    int xs = v;
#pragma unroll
    for (int o = 1; o < 64; o <<= 1) {
        int y = __shfl_up(xs, o);
        if (lane >= o) xs += y;
    }
    __shared__ int wsum[4];
    if (lane == 63) wsum[w] = xs;
    __syncthreads();
    int woff = 0;
    for (int k = 0; k < w; ++k) woff += wsum[k];
    if (i < N) {
        int rp = boff[blockIdx.x] + woff + xs - v;
        rowptr[i] = rp;
        cursor[i] = rp;
        dinv[i] = rsqrtf((float)v + 1.0f);
    }
    if (i == N) rowptr[N] = E;
}

// ---------------- fused: g0 = (x @ W0) * dinv  (+ CSR fill) ----------------
// xw0: 64 rows/block, 16 chunks of 32 cols. Coalesced global_load_lds staging
// (linear LDS dest, inverse-swizzled per-lane global source), XOR-swizzled
// ds_read_b128 on the compute side (conflict-free), LDS double buffer, one
// __syncthreads per chunk (stage c+1 issued before compute c). 4-wave k-split
// reduced via padded-LDS epilogue. W0 via wave-uniform s_load.

constexpr int RPB  = 64;          // rows per block
constexpr int KCH  = 32;          // cols per chunk (128 B per row)
constexpr int NCHK = FIN / KCH;   // 16

typedef const __attribute__((address_space(1))) void* gas_ptr;
typedef __attribute__((address_space(3))) void* las_ptr;

__global__ void __launch_bounds__(256) k_xw0_fill(
    const float* __restrict__ x, const float* __restrict__ W0,
    const float* __restrict__ dinv, float* __restrict__ g0, int N, int nbx,
    const int* __restrict__ src, const int* __restrict__ dst,
    int* __restrict__ cursor, int* __restrict__ esrc, int E) {
    __shared__ float redbuf[256 * 17];  // 17408 B; first 4096 floats alias 2 stage bufs
    float* buf0 = redbuf;
    float* buf1 = redbuf + 2048;

    if ((int)blockIdx.x >= nbx) {  // -------- fill blocks --------
        int e = (blockIdx.x - nbx) * 256 + threadIdx.x;
        if (e < E) {
            int p = atomicAdd(&cursor[dst[e]], 1);
            esrc[p] = src[e];
        }
        return;
    }

    const int tid = threadIdx.x;
    const int q = tid >> 6;       // wave id = k-split 0..3
    const int r = tid & 63;       // row within block
    const int row0 = blockIdx.x * RPB;
    const int lane = tid & 63;

    // stage chunk c into buf: each wave issues 2x global_load_lds (1 KB each).
    // physical LDS byte P = q*2048 + i*1024 + lane*16 (linear dest).
    // row(P) = P>>7, physSlot = lane&7; logical slot = physSlot ^ (row&7).
    auto STAGE = [&](float* buf, int c) {
#pragma unroll
        for (int i = 0; i < 2; ++i) {
            int off = q * 2048 + i * 1024;            // wave-uniform byte base
            int row = (off >> 7) + (lane >> 3);       // q*16 + i*8 + lane/8
            int sL = (lane & 7) ^ (row & 7);
            int grow = row0 + row;
            if (grow >= N) grow = N - 1;
            const float* gp = x + (size_t)grow * FIN + c * KCH + sL * 4;
            __builtin_amdgcn_global_load_lds((gas_ptr)gp,
                                             (las_ptr)((char*)buf + off), 16, 0, 0);
        }
    };

    float acc[HID];
#pragma unroll
    for (int j = 0; j < HID; ++j) acc[j] = 0.f;

    STAGE(buf0, 0);
    for (int c = 0; c < NCHK; ++c) {
        __syncthreads();  // drains vmcnt: chunk c staged by all waves; prev compute done
        if (c + 1 < NCHK) STAGE((c & 1) ? buf0 : buf1, c + 1);
        const float* bufc = (c & 1) ? buf1 : buf0;
        const float* wbase = W0 + (size_t)(c * KCH + q * 8) * HID;  // uniform -> s_load
#pragma unroll
        for (int h = 0; h < 2; ++h) {
            int sl = (q * 2 + h) ^ (r & 7);           // physical slot (swizzled read)
            float4 xv = *(const float4*)(bufc + r * 32 + sl * 4);
            const float* w = wbase + h * 4 * HID;
#pragma unroll
            for (int j = 0; j < HID; ++j) {
                acc[j] = fmaf(xv.x, w[j], acc[j]);
                acc[j] = fmaf(xv.y, w[HID + j], acc[j]);
                acc[j] = fmaf(xv.z, w[2 * HID + j], acc[j]);
                acc[j] = fmaf(xv.w, w[3 * HID + j], acc[j]);
            }
        }
    }

    // cross-wave k-split reduction via padded LDS (stride 17: conflict-free)
    __syncthreads();
#pragma unroll
    for (int j = 0; j < HID; ++j) redbuf[tid * 17 + j] = acc[j];
    __syncthreads();
    if (tid < RPB) {
        int row = row0 + tid;
        if (row < N) {
            float dv = dinv[row];
            float4* gp = (float4*)(g0 + (size_t)row * HID);
#pragma unroll
            for (int qq = 0; qq < 4; ++qq) {
                float4 v;
#pragma unroll
                for (int u = 0; u < 4; ++u) {
                    int j = qq * 4 + u;
                    float s = redbuf[tid * 17 + j] + redbuf[(tid + 64) * 17 + j] +
                              redbuf[(tid + 128) * 17 + j] + redbuf[(tid + 192) * 17 + j];
                    (&v.x)[u] = s * dv;
                }
                gp[qq] = v;
            }
        }
    }
}

// ---------------- pull aggregation (wave per dst row, batched gathers) -------

__global__ void k_pull0(const int* __restrict__ rowptr, const int* __restrict__ esrc,
                        const float* __restrict__ g0, float* __restrict__ s0, int N) {
    int wid = (blockIdx.x * 256 + threadIdx.x) >> 6;
    if (wid >= N) return;
    int lane = threadIdx.x & 63;
    int grp = lane >> 4, j = lane & 15;
    int e0 = rowptr[wid], e1 = rowptr[wid + 1];
    float acc = 0.f;
    for (int base = e0; base < e1; base += 16) {
        int p = base + (lane & 15);
        int v = (p < e1) ? esrc[p] : 0;
#pragma unroll
        for (int u = 0; u < 4; ++u) {
            int k = grp + 4 * u;
            int idx = __shfl(v, k);
            if (base + k < e1) acc += g0[(size_t)idx * HID + j];
        }
    }
    acc += __shfl_xor(acc, 16);
    acc += __shfl_xor(acc, 32);
    if (grp == 0)
        s0[(size_t)wid * HID + j] = acc + g0[(size_t)wid * HID + j];
}

__global__ void k_h1w1(const float* __restrict__ s0, const float* __restrict__ dinv,
                       const float* __restrict__ b0, const float* __restrict__ W1,
                       float* __restrict__ g1, int N) {
    int i = blockIdx.x * 256 + threadIdx.x;
    if (i >= N) return;
    float dv = dinv[i];
    const float4* sp = (const float4*)(s0 + (size_t)i * HID);
    float4 a = sp[0], b = sp[1], c = sp[2], d = sp[3];
    float h[HID] = {a.x, a.y, a.z, a.w, b.x, b.y, b.z, b.w,
                    c.x, c.y, c.z, c.w, d.x, d.y, d.z, d.w};
#pragma unroll
    for (int j = 0; j < HID; ++j) h[j] = fmaxf(fmaf(h[j], dv, b0[j]), 0.f);
    float o[NC];
#pragma unroll
    for (int c2 = 0; c2 < NC; ++c2) o[c2] = 0.f;
#pragma unroll
    for (int j = 0; j < HID; ++j)
#pragma unroll
        for (int c2 = 0; c2 < NC; ++c2)
            o[c2] = fmaf(h[j], W1[j * NC + c2], o[c2]);
#pragma unroll
    for (int c2 = 0; c2 < NC; ++c2)
        g1[(size_t)i * NC + c2] = o[c2] * dv;
}

__global__ void k_pull1(const int* __restrict__ rowptr, const int* __restrict__ esrc,
                        const float* __restrict__ g1, const float* __restrict__ dinv,
                        const float* __restrict__ b1, float* __restrict__ outp, int N) {
    int wid = (blockIdx.x * 256 + threadIdx.x) >> 6;
    if (wid >= N) return;
    int lane = threadIdx.x & 63;
    int grp = lane >> 3, j = lane & 7;
    int e0 = rowptr[wid], e1 = rowptr[wid + 1];
    float acc = 0.f;
    for (int base = e0; base < e1; base += 16) {
        int p = base + (lane & 15);
        int v = (p < e1) ? esrc[p] : 0;
#pragma unroll
        for (int u = 0; u < 2; ++u) {
            int k = grp + 8 * u;
            int idx = __shfl(v, k);
            if (base + k < e1 && j < NC) acc += g1[(size_t)idx * NC + j];
        }
    }
    acc += __shfl_xor(acc, 8);
    acc += __shfl_xor(acc, 16);
    acc += __shfl_xor(acc, 32);
    if (grp == 0 && j < NC)
        outp[(size_t)wid * NC + j] =
            fmaf(acc + g1[(size_t)wid * NC + j], dinv[wid], b1[j]);
}

// ---------------- launch ----------------

extern "C" void kernel_launch(void* const* d_in, const int* in_sizes, int n_in,
                              void* d_out, int out_size, void* d_ws, size_t ws_size,
                              hipStream_t stream) {
    const float* x  = (const float*)d_in[0];
    const int*   ei = (const int*)d_in[1];
    const float* W0 = (const float*)d_in[2];
    const float* b0 = (const float*)d_in[3];
    const float* W1 = (const float*)d_in[4];
    const float* b1 = (const float*)d_in[5];
    float* outp = (float*)d_out;

    int N = in_sizes[0] / FIN;
    int E = in_sizes[1] / 2;
    const int* src = ei;
    const int* dst = ei + E;

    float* fws = (float*)d_ws;
    float* g0   = fws;
    float* s0   = fws + (size_t)16 * N;
    float* g1   = fws + (size_t)32 * N;
    float* dinv = fws + (size_t)39 * N;
    int* iws    = (int*)(fws + (size_t)40 * N);
    int* rowptr = iws;                       // N+1
    int* cursor = iws + (N + 1);             // N
    int* cnt    = iws + (2 * N + 1);         // N
    int* bsum   = iws + (3 * N + 1);         // 1024
    int* boff   = iws + (3 * N + 1 + 1024);  // 1024
    int* esrc   = iws + (3 * N + 1 + 2048);  // E

    int nb = (N + 255) / 256;
    int nbx = (N + RPB - 1) / RPB;
    int nbf = (E + 255) / 256;

    hipMemsetAsync(cnt, 0, (size_t)N * sizeof(int), stream);

    k_hist<<<(E + 255) / 256, 256, 0, stream>>>(dst, cnt, E);
    k_bsum<<<nb, 256, 0, stream>>>(cnt, bsum, N);
    k_scanb<<<1, 1024, 0, stream>>>(bsum, boff, nb);
    k_rowptr<<<(N + 1 + 255) / 256, 256, 0, stream>>>(cnt, boff, rowptr, cursor, dinv, N, E);

    k_xw0_fill<<<nbx + nbf, 256, 0, stream>>>(x, W0, dinv, g0, N, nbx,
                                              src, dst, cursor, esrc, E);

    k_pull0<<<(int)(((size_t)N * 64 + 255) / 256), 256, 0, stream>>>(rowptr, esrc, g0, s0, N);
    k_h1w1<<<nb, 256, 0, stream>>>(s0, dinv, b0, W1, g1, N);
    k_pull1<<<(int)(((size_t)N * 64 + 255) / 256), 256, 0, stream>>>(rowptr, esrc, g1, dinv, b1, outp, N);
}